// Round 11
// baseline (306.761 us; speedup 1.0000x reference)
//
#include <hip/hip_runtime.h>
#include <hip/hip_bf16.h>
#include <cstdint>

#define B_SZ 2
#define S_LEN 4096
#define R_TOT 8192      // B*S
#define DM 2048
#define NH 16
#define DK 128
#define NFEAT 8
#define CHUNK 128
#define NCHUNK 32       // S_LEN / CHUNK
#define KSPL 512        // thin GEMM K-split size
#define EPSF 1e-6f

typedef short bf16x8_t __attribute__((ext_vector_type(8)));
typedef float f32x4_t __attribute__((ext_vector_type(4)));

__device__ __forceinline__ ushort f2bf(float f) {
  uint32_t u = __float_as_uint(f);
  u += 0x7FFF + ((u >> 16) & 1);           // RNE
  return (ushort)(u >> 16);
}
__device__ __forceinline__ float bf2f(ushort u) {
  return __uint_as_float(((uint32_t)u) << 16);
}

// ---------------- prep: w_v/w_o cast | omega-fold q/k (v-cast moved to thin_cast) ----------------
// flat grid: [0,8192) weight casts; [8192,8448) folds
__global__ __launch_bounds__(256) void prep_kernel(const float* __restrict__ w_v,
                                                   const float* __restrict__ w_o,
                                                   const float* __restrict__ w_q,
                                                   const float* __restrict__ w_k,
                                                   const float* __restrict__ omega,
                                                   ushort* __restrict__ wvb,
                                                   ushort* __restrict__ wob,
                                                   ushort* __restrict__ oqb,
                                                   ushort* __restrict__ okb) {
  const int bid = blockIdx.x;
  if (bid < 8192) {                        // weights: 2 x 4096 blocks
    const float* src = (bid >= 4096) ? w_o : w_v;
    ushort* dst = (bid >= 4096) ? wob : wvb;
    const int i = (bid & 4095) * 256 + threadIdx.x;
    float4 f = reinterpret_cast<const float4*>(src)[i];
    ushort4 o;
    o.x = f2bf(f.x); o.y = f2bf(f.y); o.z = f2bf(f.z); o.w = f2bf(f.w);
    reinterpret_cast<ushort4*>(dst)[i] = o;
  } else {                                 // folds: 2 x 16 x 8 blocks
    __shared__ float som[NFEAT * DK];
    const int fb = bid - 8192;
    const int z = fb >> 7, h = (fb >> 3) & 15, jb = fb & 7;
    const float* W = z ? w_k : w_q;
    ushort* O = z ? okb : oqb;
    const int j = jb * 256 + threadIdx.x;
    for (int i = threadIdx.x; i < NFEAT * DK; i += 256) som[i] = omega[i];
    __syncthreads();
    float acc[NFEAT] = {0.f, 0.f, 0.f, 0.f, 0.f, 0.f, 0.f, 0.f};
    for (int d = 0; d < DK; d++) {
      const float w = W[(size_t)(h * DK + d) * DM + j];
#pragma unroll
      for (int n = 0; n < NFEAT; n++) acc[n] += w * som[n * DK + d];
    }
#pragma unroll
    for (int n = 0; n < NFEAT; n++) O[(size_t)(h * NFEAT + n) * DM + j] = f2bf(acc[n]);
  }
}

// 16-MFMA cluster: acc[mb..mb+3][0..3] += Am x Bn
#define MFMA_BLK(mb, A0_, A1_, A2_, A3_, B0_, B1_, B2_, B3_)                                  \
  acc[mb + 0][0] = __builtin_amdgcn_mfma_f32_16x16x32_bf16(A0_, B0_, acc[mb + 0][0], 0, 0, 0); \
  acc[mb + 1][0] = __builtin_amdgcn_mfma_f32_16x16x32_bf16(A1_, B0_, acc[mb + 1][0], 0, 0, 0); \
  acc[mb + 2][0] = __builtin_amdgcn_mfma_f32_16x16x32_bf16(A2_, B0_, acc[mb + 2][0], 0, 0, 0); \
  acc[mb + 3][0] = __builtin_amdgcn_mfma_f32_16x16x32_bf16(A3_, B0_, acc[mb + 3][0], 0, 0, 0); \
  acc[mb + 0][1] = __builtin_amdgcn_mfma_f32_16x16x32_bf16(A0_, B1_, acc[mb + 0][1], 0, 0, 0); \
  acc[mb + 1][1] = __builtin_amdgcn_mfma_f32_16x16x32_bf16(A1_, B1_, acc[mb + 1][1], 0, 0, 0); \
  acc[mb + 2][1] = __builtin_amdgcn_mfma_f32_16x16x32_bf16(A2_, B1_, acc[mb + 2][1], 0, 0, 0); \
  acc[mb + 3][1] = __builtin_amdgcn_mfma_f32_16x16x32_bf16(A3_, B1_, acc[mb + 3][1], 0, 0, 0); \
  acc[mb + 0][2] = __builtin_amdgcn_mfma_f32_16x16x32_bf16(A0_, B2_, acc[mb + 0][2], 0, 0, 0); \
  acc[mb + 1][2] = __builtin_amdgcn_mfma_f32_16x16x32_bf16(A1_, B2_, acc[mb + 1][2], 0, 0, 0); \
  acc[mb + 2][2] = __builtin_amdgcn_mfma_f32_16x16x32_bf16(A2_, B2_, acc[mb + 2][2], 0, 0, 0); \
  acc[mb + 3][2] = __builtin_amdgcn_mfma_f32_16x16x32_bf16(A3_, B2_, acc[mb + 3][2], 0, 0, 0); \
  acc[mb + 0][3] = __builtin_amdgcn_mfma_f32_16x16x32_bf16(A0_, B3_, acc[mb + 0][3], 0, 0, 0); \
  acc[mb + 1][3] = __builtin_amdgcn_mfma_f32_16x16x32_bf16(A1_, B3_, acc[mb + 1][3], 0, 0, 0); \
  acc[mb + 2][3] = __builtin_amdgcn_mfma_f32_16x16x32_bf16(A2_, B3_, acc[mb + 2][3], 0, 0, 0); \
  acc[mb + 3][3] = __builtin_amdgcn_mfma_f32_16x16x32_bf16(A3_, B3_, acc[mb + 3][3], 0, 0, 0);

// ---------------- 256x256 pipelined bf16 GEMM: C = A * B^T ----------------
// r6 structure; round-11 change: per-phase sched_barrier(0) removed (let the
// scheduler blend register-only MFMA across phase boundaries).
template<int BF16OUT>
__global__ __launch_bounds__(512, 1) void gemm256(const ushort* __restrict__ A,
                                                  const ushort* __restrict__ Bm,
                                                  void* __restrict__ Cv,
                                                  int M, int N, int K) {
  __shared__ ushort lds[8 * 8192];     // [buf][A/B][kh] x (256*32), 128 KB
  const int tid = threadIdx.x;
  const int wave = tid >> 6, lane = tid & 63;
  const int wm = wave >> 2, wn = wave & 3;
  const int NKT = K >> 6;

  // bijective XCD swizzle (gridDim.x % 8 == 0)
  const int nb = N >> 8;
  const int cpx = gridDim.x >> 3;
  const int swz = (blockIdx.x & 7) * cpx + (blockIdx.x >> 3);
  const int bx = swz % nb, by = swz / nb;
  const int m0 = by * 256, n0 = bx * 256;

  auto stage = [&](int bufi, int ab, int kh, int kt, const ushort* G, int r0) {
    ushort* Lr = lds + (((bufi << 1) | ab) << 1 | kh) * 8192;
#pragma unroll
    for (int j = 0; j < 2; j++) {
      const int c = j * 512 + wave * 64 + lane;
      const int row = c >> 2, slot = c & 3;
      const int ss = slot ^ ((row >> 1) & 3);
      const ushort* g = G + (size_t)(r0 + row) * K + kt * 64 + kh * 32 + ss * 8;
      __builtin_amdgcn_global_load_lds(
          (const __attribute__((address_space(1))) void*)g,
          (__attribute__((address_space(3))) void*)(Lr + (j * 512 + wave * 64) * 8), 16, 0, 0);
    }
  };
  auto rdA = [&](int bufi, int kh, int m) -> bf16x8_t {
    const int row = wm * 128 + m * 16 + (lane & 15);
    const int slot = (lane >> 4) ^ ((row >> 1) & 3);
    return *reinterpret_cast<const bf16x8_t*>(lds + ((bufi << 2) | kh) * 8192 + row * 32 + slot * 8);
  };
  auto rdB = [&](int bufi, int kh, int nf) -> bf16x8_t {
    const int row = wn * 64 + nf * 16 + (lane & 15);
    const int slot = (lane >> 4) ^ ((row >> 1) & 3);
    return *reinterpret_cast<const bf16x8_t*>(lds + (((bufi << 1) | 1) << 1 | kh) * 8192 + row * 32 + slot * 8);
  };

  f32x4_t acc[8][4];
#pragma unroll
  for (int m = 0; m < 8; m++)
#pragma unroll
    for (int nf = 0; nf < 4; nf++) acc[m][nf] = (f32x4_t){0.f, 0.f, 0.f, 0.f};

  // prologue stages: t0 full tile + t1 kh0 (6 stages = 12 loads/wave)
  stage(0, 0, 0, 0, A, m0);  stage(0, 1, 0, 0, Bm, n0);
  stage(0, 0, 1, 0, A, m0);  stage(0, 1, 1, 0, Bm, n0);
  stage(1, 0, 0, 1, A, m0);  stage(1, 1, 0, 1, Bm, n0);
  asm volatile("s_waitcnt vmcnt(8)" ::: "memory");   // buf0-kh0 (A,B) landed
  __builtin_amdgcn_s_barrier();

  // prologue reads: the set consumed by t0.ph1
  bf16x8_t pA0 = rdA(0, 0, 0), pA1 = rdA(0, 0, 1), pA2 = rdA(0, 0, 2), pA3 = rdA(0, 0, 3);
  bf16x8_t B00 = rdB(0, 0, 0), B01 = rdB(0, 0, 1), B02 = rdB(0, 0, 2), B03 = rdB(0, 0, 3);
  bf16x8_t qA0, qA1, qA2, qA3, B10, B11, B12, B13;

  for (int t = 0; t < NKT; t++) {
    const int buf = t & 1;
    const int t1 = (t + 1 < NKT) ? t + 1 : NKT - 1;
    const int t2 = (t + 2 < NKT) ? t + 2 : NKT - 1;

    // ---- ph1: reads qA<-A(kh0,mh1); stage A-kh1(t1)->buf^1; MFMA(pA,B0)->mh0 ----
    qA0 = rdA(buf, 0, 4); qA1 = rdA(buf, 0, 5); qA2 = rdA(buf, 0, 6); qA3 = rdA(buf, 0, 7);
    stage(buf ^ 1, 0, 1, t1, A, m0);
    __builtin_amdgcn_s_setprio(1);
    MFMA_BLK(0, pA0, pA1, pA2, pA3, B00, B01, B02, B03)
    __builtin_amdgcn_s_setprio(0);
    asm volatile("s_waitcnt vmcnt(6)" ::: "memory");  // buf-kh1 (A,B) landed
    __builtin_amdgcn_s_barrier();

    // ---- ph2: reads pA<-A(kh1,mh0), B1<-B(kh1); stage B-kh1(t1)->buf^1; MFMA(qA,B0)->mh1 ----
    pA0 = rdA(buf, 1, 0); pA1 = rdA(buf, 1, 1); pA2 = rdA(buf, 1, 2); pA3 = rdA(buf, 1, 3);
    B10 = rdB(buf, 1, 0); B11 = rdB(buf, 1, 1); B12 = rdB(buf, 1, 2); B13 = rdB(buf, 1, 3);
    stage(buf ^ 1, 1, 1, t1, Bm, n0);
    __builtin_amdgcn_s_setprio(1);
    MFMA_BLK(4, qA0, qA1, qA2, qA3, B00, B01, B02, B03)
    __builtin_amdgcn_s_setprio(0);
    __builtin_amdgcn_s_barrier();

    // ---- ph3: reads qA<-A(kh1,mh1); stage A-kh0(t2)->buf; MFMA(pA,B1)->mh0 ----
    qA0 = rdA(buf, 1, 4); qA1 = rdA(buf, 1, 5); qA2 = rdA(buf, 1, 6); qA3 = rdA(buf, 1, 7);
    stage(buf, 0, 0, t2, A, m0);
    __builtin_amdgcn_s_setprio(1);
    MFMA_BLK(0, pA0, pA1, pA2, pA3, B10, B11, B12, B13)
    __builtin_amdgcn_s_setprio(0);
    asm volatile("s_waitcnt vmcnt(6)" ::: "memory");  // buf^1-kh0 (A,B) landed
    __builtin_amdgcn_s_barrier();

    // ---- ph4: reads pA<-A'(kh0,mh0), B0<-B'(kh0) from buf^1; stage B-kh0(t2)->buf; MFMA(qA,B1)->mh1 ----
    pA0 = rdA(buf ^ 1, 0, 0); pA1 = rdA(buf ^ 1, 0, 1); pA2 = rdA(buf ^ 1, 0, 2); pA3 = rdA(buf ^ 1, 0, 3);
    B00 = rdB(buf ^ 1, 0, 0); B01 = rdB(buf ^ 1, 0, 1); B02 = rdB(buf ^ 1, 0, 2); B03 = rdB(buf ^ 1, 0, 3);
    stage(buf, 1, 0, t2, Bm, n0);
    __builtin_amdgcn_s_setprio(1);
    MFMA_BLK(4, qA0, qA1, qA2, qA3, B10, B11, B12, B13)
    __builtin_amdgcn_s_setprio(0);
    __builtin_amdgcn_s_barrier();
  }
  asm volatile("s_waitcnt vmcnt(0)" ::: "memory");

  // epilogue: C/D layout col = lane&15, row = (lane>>4)*4 + reg
#pragma unroll
  for (int m = 0; m < 8; m++) {
    const int rb = m0 + wm * 128 + m * 16 + (lane >> 4) * 4;
#pragma unroll
    for (int nf = 0; nf < 4; nf++) {
      const int col = n0 + wn * 64 + nf * 16 + (lane & 15);
#pragma unroll
      for (int r = 0; r < 4; r++) {
        const float val = acc[m][nf][r];
        if (BF16OUT)
          ((ushort*)Cv)[(size_t)(rb + r) * N + col] = f2bf(val);
        else
          ((float*)Cv)[(size_t)(rb + r) * N + col] = val;
      }
    }
  }
}

// ---------------- merged: thin GEMM (r9 version) + v fp32->bf16 cast ----------------
// grid (132, 64, 2): x<4 -> GEMM (split=x, m0=y*128, which=z);
// x>=4 -> v-cast block, cast_bid = (x-4)*128 + y*2 + z in [0,16384).
__global__ __launch_bounds__(256) void thin_cast(const float* __restrict__ qin,
                                                 const float* __restrict__ kin,
                                                 const float* __restrict__ vin,
                                                 const ushort* __restrict__ oqb,
                                                 const ushort* __restrict__ okb,
                                                 float* __restrict__ P,
                                                 ushort* __restrict__ xb) {
  __shared__ ushort lds_a[128 * 32];
  __shared__ ushort lds_b[128 * 32];
  const int t = threadIdx.x;

  if (blockIdx.x >= 4) {
    // ---- v cast path ----
    const int cast_bid = (blockIdx.x - 4) * 128 + blockIdx.y * 2 + blockIdx.z;
    const int i = cast_bid * 256 + t;
    float4 f = reinterpret_cast<const float4*>(vin)[i];
    ushort4 o;
    o.x = f2bf(f.x); o.y = f2bf(f.y); o.z = f2bf(f.z); o.w = f2bf(f.w);
    reinterpret_cast<ushort4*>(xb)[i] = o;
    return;
  }

  // ---- thin GEMM path (r9) ----
  const int which = blockIdx.z;
  const float* A = which ? kin : qin;
  const ushort* Bm = which ? okb : oqb;
  const int wave = t >> 6, lane = t & 63;
  const int spl = blockIdx.x;
  const int m0 = blockIdx.y * 128;
  const int kb = spl * KSPL;
  const int wm = wave >> 1, wn = wave & 1;

  f32x4_t acc[4][4];
#pragma unroll
  for (int i = 0; i < 4; i++)
#pragma unroll
    for (int j = 0; j < 4; j++) acc[i][j] = (f32x4_t){0.f, 0.f, 0.f, 0.f};

  const int srow = lane >> 2;
  const int skoff = (lane & 3) * 8;

  for (int k0 = kb; k0 < kb + KSPL; k0 += 32) {
    // A: fp32 load + convert + LDS write (fused cast)
#pragma unroll
    for (int j = 0; j < 2; j++) {
      const int g = j * 256 + t;
      const int row = g >> 2, slot = g & 3;
      const float4* gp = reinterpret_cast<const float4*>(A + (size_t)(m0 + row) * DM + k0 + slot * 8);
      const float4 f0 = gp[0], f1 = gp[1];
      union { ushort u[8]; bf16x8_t v; } pk;
      pk.u[0] = f2bf(f0.x); pk.u[1] = f2bf(f0.y); pk.u[2] = f2bf(f0.z); pk.u[3] = f2bf(f0.w);
      pk.u[4] = f2bf(f1.x); pk.u[5] = f2bf(f1.y); pk.u[6] = f2bf(f1.z); pk.u[7] = f2bf(f1.w);
      *reinterpret_cast<bf16x8_t*>(lds_a + row * 32 + slot * 8) = pk.v;
    }
    // B: bf16 via async global->LDS
#pragma unroll
    for (int i = 0; i < 2; i++) {
      const int rgrp = i * 4 + wave;
      const int row = rgrp * 16 + srow;
      const ushort* gb = Bm + (size_t)row * DM + (k0 + skoff);
      __builtin_amdgcn_global_load_lds(
          (const __attribute__((address_space(1))) void*)gb,
          (__attribute__((address_space(3))) void*)(lds_b + rgrp * 512), 16, 0, 0);
    }
    __syncthreads();
    bf16x8_t af[4], bfr[4];
#pragma unroll
    for (int i = 0; i < 4; i++) {
      af[i]  = *reinterpret_cast<const bf16x8_t*>(
          lds_a + (wm * 64 + i * 16 + (lane & 15)) * 32 + (lane >> 4) * 8);
      bfr[i] = *reinterpret_cast<const bf16x8_t*>(
          lds_b + (wn * 64 + i * 16 + (lane & 15)) * 32 + (lane >> 4) * 8);
    }
#pragma unroll
    for (int i = 0; i < 4; i++)
#pragma unroll
      for (int j = 0; j < 4; j++)
        acc[i][j] = __builtin_amdgcn_mfma_f32_16x16x32_bf16(af[i], bfr[j], acc[i][j], 0, 0, 0);
    __syncthreads();
  }

  float* Pp = P + (size_t)which * (4ull * R_TOT * 128) + (size_t)spl * ((size_t)R_TOT * 128);
#pragma unroll
  for (int i = 0; i < 4; i++) {
    const int rb = m0 + wm * 64 + i * 16 + (lane >> 4) * 4;
#pragma unroll
    for (int j = 0; j < 4; j++) {
      const int col = wn * 64 + j * 16 + (lane & 15);
#pragma unroll
      for (int r = 0; r < 4; r++)
        Pp[(size_t)(rb + r) * 128 + col] = acc[i][j][r];
    }
  }
}

// ---------------- merged performer features from split-K partials ----------------
__global__ __launch_bounds__(256) void feat2x2(const float* __restrict__ P,
                                               float* __restrict__ qf,
                                               float* __restrict__ kf) {
  const int which = blockIdx.y;
  const float* Pb = P + (size_t)which * (4ull * R_TOT * 128);
  float* F = which ? kf : qf;
  const int g = blockIdx.x * 256 + threadIdx.x;     // 131072 total
  const int row = g >> 4, h = g & 15;
  float4 a = {0.f, 0.f, 0.f, 0.f}, c = {0.f, 0.f, 0.f, 0.f};
#pragma unroll
  for (int s = 0; s < 4; s++) {
    const float4* xp = reinterpret_cast<const float4*>(
        Pb + (size_t)s * ((size_t)R_TOT * 128) + (size_t)row * 128 + h * NFEAT);
    const float4 u = xp[0], w = xp[1];
    a.x += u.x; a.y += u.y; a.z += u.z; a.w += u.w;
    c.x += w.x; c.y += w.y; c.z += w.z; c.w += w.w;
  }
  float x[8] = {a.x, a.y, a.z, a.w, c.x, c.y, c.z, c.w};
  float f[8], s = 0.f;
#pragma unroll
  for (int n = 0; n < 8; n++) { f[n] = __expf(-0.5f * x[n] * x[n]); s += f[n]; }
  const float inv = 1.f / (s + EPSF);
  const int b = row >> 12, sidx = row & 4095;
  float* out = F + ((size_t)(h * 2 + b) * 4096 + sidx) * 8;
  float4 o0 = {f[0] * inv, f[1] * inv, f[2] * inv, f[3] * inv};
  float4 o1 = {f[4] * inv, f[5] * inv, f[6] * inv, f[7] * inv};
  reinterpret_cast<float4*>(out)[0] = o0;
  reinterpret_cast<float4*>(out)[1] = o1;
}

// ---------------- per-chunk partial sums: KV_c[8][128], K_c[8] ----------------
__global__ __launch_bounds__(128) void chunk_sum_kernel(const float* __restrict__ KF,
                                                        const ushort* __restrict__ VH,
                                                        float* __restrict__ CKV,
                                                        float* __restrict__ CK) {
  const int cid = blockIdx.x;
  const int c = cid & 31, bh = cid >> 5, b = bh >> 4, h = bh & 15;
  const int d = threadIdx.x;
  __shared__ float s_kf[CHUNK * 8];
  const size_t fbase = ((size_t)(h * 2 + b) * 4096 + (size_t)c * CHUNK) * 8;
  {
    float4 a0 = *reinterpret_cast<const float4*>(KF + fbase + d * 8);
    float4 a1 = *reinterpret_cast<const float4*>(KF + fbase + d * 8 + 4);
    *reinterpret_cast<float4*>(s_kf + d * 8) = a0;
    *reinterpret_cast<float4*>(s_kf + d * 8 + 4) = a1;
  }
  __syncthreads();
  float kv[8] = {0, 0, 0, 0, 0, 0, 0, 0};
  float ks = 0.f;
  const ushort* vp = VH + ((size_t)b * S_LEN + (size_t)c * CHUNK) * DM + h * DK + d;
  for (int s = 0; s < CHUNK; s++) {
    const float v = bf2f(vp[(size_t)s * DM]);
#pragma unroll
    for (int n = 0; n < 8; n++) kv[n] += s_kf[s * 8 + n] * v;
    ks += s_kf[s * 8 + (d & 7)];
  }
#pragma unroll
  for (int n = 0; n < 8; n++) CKV[((size_t)cid * 8 + n) * 128 + d] = kv[n];
  if (d < 8) CK[cid * 8 + d] = ks;
}

// ---------------- exclusive prefix over chunks, parallel ----------------
__global__ __launch_bounds__(128) void chunk_scan2(float* __restrict__ CKV,
                                                   float* __restrict__ CK) {
  const int bh = blockIdx.x >> 3, n = blockIdx.x & 7;
  const int d = threadIdx.x;
  float v[NCHUNK];
#pragma unroll
  for (int c = 0; c < NCHUNK; c++)
    v[c] = CKV[((size_t)(bh * NCHUNK + c) * 8 + n) * 128 + d];
  float run = 0.f;
#pragma unroll
  for (int c = 0; c < NCHUNK; c++) {
    const float tv = v[c];
    CKV[((size_t)(bh * NCHUNK + c) * 8 + n) * 128 + d] = run;
    run += tv;
  }
  if (d < 32) {
    const int i = (bh * NCHUNK + d) * 8 + n;
    const float orig = CK[i];
    float inc = orig;
#pragma unroll
    for (int off = 1; off < 32; off <<= 1) {
      const float o = __shfl_up(inc, off, 32);
      if (d >= off) inc += o;
    }
    CK[i] = inc - orig;   // exclusive
  }
}

// ---------------- in-chunk causal scan + query ----------------
__global__ __launch_bounds__(128) void attn_scan_kernel(const float* __restrict__ QF,
                                                        const float* __restrict__ KF,
                                                        const ushort* __restrict__ VH,
                                                        const float* __restrict__ CKV,
                                                        const float* __restrict__ CK,
                                                        ushort* __restrict__ AO) {
  const int cid = blockIdx.x;
  const int c = cid & 31, bh = cid >> 5, b = bh >> 4, h = bh & 15;
  const int d = threadIdx.x;
  __shared__ float s_qf[CHUNK * 8];
  __shared__ float s_kf[CHUNK * 8];
  const size_t fbase = ((size_t)(h * 2 + b) * 4096 + (size_t)c * CHUNK) * 8;
  {
    float4 a0 = *reinterpret_cast<const float4*>(QF + fbase + d * 8);
    float4 a1 = *reinterpret_cast<const float4*>(QF + fbase + d * 8 + 4);
    float4 b0 = *reinterpret_cast<const float4*>(KF + fbase + d * 8);
    float4 b1 = *reinterpret_cast<const float4*>(KF + fbase + d * 8 + 4);
    *reinterpret_cast<float4*>(s_qf + d * 8) = a0;
    *reinterpret_cast<float4*>(s_qf + d * 8 + 4) = a1;
    *reinterpret_cast<float4*>(s_kf + d * 8) = b0;
    *reinterpret_cast<float4*>(s_kf + d * 8 + 4) = b1;
  }
  float kv[8], krun[8];
#pragma unroll
  for (int n = 0; n < 8; n++) kv[n] = CKV[((size_t)cid * 8 + n) * 128 + d];
#pragma unroll
  for (int n = 0; n < 8; n++) krun[n] = CK[cid * 8 + n];
  __syncthreads();
  const size_t row0 = (size_t)b * S_LEN + (size_t)c * CHUNK;
  const ushort* vp = VH + row0 * DM + h * DK + d;
  ushort* op = AO + row0 * DM + h * DK + d;
  for (int s = 0; s < CHUNK; s++) {
    const float v = bf2f(vp[(size_t)s * DM]);
    float num = 0.f, den = 0.f;
#pragma unroll
    for (int n = 0; n < 8; n++) {
      const float kf = s_kf[s * 8 + n];
      kv[n] += kf * v;       // inclusive update first
      krun[n] += kf;
      const float qf = s_qf[s * 8 + n];
      num += qf * kv[n];
      den += qf * krun[n];
    }
    op[(size_t)s * DM] = f2bf(num / (den + EPSF));
  }
}

extern "C" void kernel_launch(void* const* d_in, const int* in_sizes, int n_in,
                              void* d_out, int out_size, void* d_ws, size_t ws_size,
                              hipStream_t stream) {
  const float* q     = (const float*)d_in[0];
  const float* k     = (const float*)d_in[1];
  const float* v     = (const float*)d_in[2];
  const float* w_q   = (const float*)d_in[3];
  const float* w_k   = (const float*)d_in[4];
  const float* w_v   = (const float*)d_in[5];
  const float* w_o   = (const float*)d_in[6];
  const float* omega = (const float*)d_in[7];

  // ---- workspace layout (~93 MB) ----
  char* ws = (char*)d_ws;
  const size_t DD2 = (size_t)DM * DM * 2;            //  8 MB
  const size_t OD2 = (size_t)NH * NFEAT * DM * 2;    //  0.5 MB
  const size_t RD2 = (size_t)R_TOT * DM * 2;         // 32 MB
  const size_t X4  = (size_t)R_TOT * NH * NFEAT * 4; //  4 MB

  ushort* wvb = (ushort*)(ws);
  ushort* wob = (ushort*)(ws + DD2);
  ushort* oqb = (ushort*)(ws + 2 * DD2);
  ushort* okb = (ushort*)(ws + 2 * DD2 + OD2);
  ushort* xb  = (ushort*)(ws + 2 * DD2 + 2 * OD2);             // bf16 staging: v -> attn-out
  ushort* vhb = (ushort*)(ws + 2 * DD2 + 2 * OD2 + RD2);
  float*  xp4 = (float*) (ws + 2 * DD2 + 2 * OD2 + RD2);       // 2x4 fp32 partials (32MB) alias vhb (dead then)
  float*  qf  = (float*) (ws + 2 * DD2 + 2 * OD2 + 2 * RD2);
  float*  kf  = (float*) (ws + 2 * DD2 + 2 * OD2 + 2 * RD2 + X4);
  float*  ckv = (float*) (ws + 2 * DD2 + 2 * OD2 + 2 * RD2 + 2 * X4);
  float*  ck  = (float*) (ws + 2 * DD2 + 2 * OD2 + 2 * RD2 + 3 * X4);
  ushort* ao  = xb;

  // prep: weight casts + folds (v-cast moved into thin_cast)
  prep_kernel<<<dim3(8448), 256, 0, stream>>>(w_v, w_o, w_q, w_k, omega,
                                              wvb, wob, oqb, okb);

  // q + k features (split-K thin GEMM, fused q/k cast) + v-cast, one launch
  thin_cast<<<dim3(132, 64, 2), 256, 0, stream>>>(q, k, v, oqb, okb, xp4, xb);
  feat2x2<<<dim3(R_TOT * NH / 256, 2), 256, 0, stream>>>(xp4, qf, kf);

  // v projection (overwrites xp4 region -- xp4 is dead now)
  gemm256<1><<<dim3((R_TOT / 256) * (DM / 256)), 512, 0, stream>>>(xb, wvb, (void*)vhb, R_TOT, DM, DM);

  // causal linear attention scan
  chunk_sum_kernel<<<dim3(B_SZ * NH * NCHUNK), 128, 0, stream>>>(kf, vhb, ckv, ck);
  chunk_scan2<<<dim3(B_SZ * NH * 8), 128, 0, stream>>>(ckv, ck);
  attn_scan_kernel<<<dim3(B_SZ * NH * NCHUNK), 128, 0, stream>>>(qf, kf, vhb, ckv, ck, ao);

  // output projection
  gemm256<0><<<dim3((R_TOT / 256) * (DM / 256)), 512, 0, stream>>>(ao, wob, d_out, R_TOT, DM, DM);
}

// Round 12
// 289.921 us; speedup vs baseline: 1.0581x; 1.0581x over previous
//
#include <hip/hip_runtime.h>
#include <hip/hip_bf16.h>
#include <cstdint>

#define B_SZ 2
#define S_LEN 4096
#define R_TOT 8192      // B*S
#define DM 2048
#define NH 16
#define DK 128
#define NFEAT 8
#define CHUNK 128
#define NCHUNK 32       // S_LEN / CHUNK
#define KSPL 512        // thin GEMM K-split size
#define EPSF 1e-6f

typedef short bf16x8_t __attribute__((ext_vector_type(8)));
typedef float f32x4_t __attribute__((ext_vector_type(4)));

__device__ __forceinline__ ushort f2bf(float f) {
  uint32_t u = __float_as_uint(f);
  u += 0x7FFF + ((u >> 16) & 1);           // RNE
  return (ushort)(u >> 16);
}
__device__ __forceinline__ float bf2f(ushort u) {
  return __uint_as_float(((uint32_t)u) << 16);
}

// ---------------- prep: w_v/w_o cast | omega-fold q/k (v-cast lives in gemm_thin2) ----------------
// flat grid: [0,8192) weight casts; [8192,8448) folds
__global__ __launch_bounds__(256) void prep_kernel(const float* __restrict__ w_v,
                                                   const float* __restrict__ w_o,
                                                   const float* __restrict__ w_q,
                                                   const float* __restrict__ w_k,
                                                   const float* __restrict__ omega,
                                                   ushort* __restrict__ wvb,
                                                   ushort* __restrict__ wob,
                                                   ushort* __restrict__ oqb,
                                                   ushort* __restrict__ okb) {
  const int bid = blockIdx.x;
  if (bid < 8192) {                        // weights: 2 x 4096 blocks
    const float* src = (bid >= 4096) ? w_o : w_v;
    ushort* dst = (bid >= 4096) ? wob : wvb;
    const int i = (bid & 4095) * 256 + threadIdx.x;
    float4 f = reinterpret_cast<const float4*>(src)[i];
    ushort4 o;
    o.x = f2bf(f.x); o.y = f2bf(f.y); o.z = f2bf(f.z); o.w = f2bf(f.w);
    reinterpret_cast<ushort4*>(dst)[i] = o;
  } else {                                 // folds: 2 x 16 x 8 blocks
    __shared__ float som[NFEAT * DK];
    const int fb = bid - 8192;
    const int z = fb >> 7, h = (fb >> 3) & 15, jb = fb & 7;
    const float* W = z ? w_k : w_q;
    ushort* O = z ? okb : oqb;
    const int j = jb * 256 + threadIdx.x;
    for (int i = threadIdx.x; i < NFEAT * DK; i += 256) som[i] = omega[i];
    __syncthreads();
    float acc[NFEAT] = {0.f, 0.f, 0.f, 0.f, 0.f, 0.f, 0.f, 0.f};
    for (int d = 0; d < DK; d++) {
      const float w = W[(size_t)(h * DK + d) * DM + j];
#pragma unroll
      for (int n = 0; n < NFEAT; n++) acc[n] += w * som[n * DK + d];
    }
#pragma unroll
    for (int n = 0; n < NFEAT; n++) O[(size_t)(h * NFEAT + n) * DM + j] = f2bf(acc[n]);
  }
}

// 16-MFMA cluster: acc[mb..mb+3][0..3] += Am x Bn
#define MFMA_BLK(mb, A0_, A1_, A2_, A3_, B0_, B1_, B2_, B3_)                                  \
  acc[mb + 0][0] = __builtin_amdgcn_mfma_f32_16x16x32_bf16(A0_, B0_, acc[mb + 0][0], 0, 0, 0); \
  acc[mb + 1][0] = __builtin_amdgcn_mfma_f32_16x16x32_bf16(A1_, B0_, acc[mb + 1][0], 0, 0, 0); \
  acc[mb + 2][0] = __builtin_amdgcn_mfma_f32_16x16x32_bf16(A2_, B0_, acc[mb + 2][0], 0, 0, 0); \
  acc[mb + 3][0] = __builtin_amdgcn_mfma_f32_16x16x32_bf16(A3_, B0_, acc[mb + 3][0], 0, 0, 0); \
  acc[mb + 0][1] = __builtin_amdgcn_mfma_f32_16x16x32_bf16(A0_, B1_, acc[mb + 0][1], 0, 0, 0); \
  acc[mb + 1][1] = __builtin_amdgcn_mfma_f32_16x16x32_bf16(A1_, B1_, acc[mb + 1][1], 0, 0, 0); \
  acc[mb + 2][1] = __builtin_amdgcn_mfma_f32_16x16x32_bf16(A2_, B1_, acc[mb + 2][1], 0, 0, 0); \
  acc[mb + 3][1] = __builtin_amdgcn_mfma_f32_16x16x32_bf16(A3_, B1_, acc[mb + 3][1], 0, 0, 0); \
  acc[mb + 0][2] = __builtin_amdgcn_mfma_f32_16x16x32_bf16(A0_, B2_, acc[mb + 0][2], 0, 0, 0); \
  acc[mb + 1][2] = __builtin_amdgcn_mfma_f32_16x16x32_bf16(A1_, B2_, acc[mb + 1][2], 0, 0, 0); \
  acc[mb + 2][2] = __builtin_amdgcn_mfma_f32_16x16x32_bf16(A2_, B2_, acc[mb + 2][2], 0, 0, 0); \
  acc[mb + 3][2] = __builtin_amdgcn_mfma_f32_16x16x32_bf16(A3_, B2_, acc[mb + 3][2], 0, 0, 0); \
  acc[mb + 0][3] = __builtin_amdgcn_mfma_f32_16x16x32_bf16(A0_, B3_, acc[mb + 0][3], 0, 0, 0); \
  acc[mb + 1][3] = __builtin_amdgcn_mfma_f32_16x16x32_bf16(A1_, B3_, acc[mb + 1][3], 0, 0, 0); \
  acc[mb + 2][3] = __builtin_amdgcn_mfma_f32_16x16x32_bf16(A2_, B3_, acc[mb + 2][3], 0, 0, 0); \
  acc[mb + 3][3] = __builtin_amdgcn_mfma_f32_16x16x32_bf16(A3_, B3_, acc[mb + 3][3], 0, 0, 0);

// ---------------- 256x256 pipelined bf16 GEMM: C = A * B^T ----------------
// (frozen: r6/r9 version verbatim)
template<int BF16OUT>
__global__ __launch_bounds__(512, 1) void gemm256(const ushort* __restrict__ A,
                                                  const ushort* __restrict__ Bm,
                                                  void* __restrict__ Cv,
                                                  int M, int N, int K) {
  __shared__ ushort lds[8 * 8192];     // [buf][A/B][kh] x (256*32), 128 KB
  const int tid = threadIdx.x;
  const int wave = tid >> 6, lane = tid & 63;
  const int wm = wave >> 2, wn = wave & 3;
  const int NKT = K >> 6;

  // bijective XCD swizzle (gridDim.x % 8 == 0)
  const int nb = N >> 8;
  const int cpx = gridDim.x >> 3;
  const int swz = (blockIdx.x & 7) * cpx + (blockIdx.x >> 3);
  const int bx = swz % nb, by = swz / nb;
  const int m0 = by * 256, n0 = bx * 256;

  auto stage = [&](int bufi, int ab, int kh, int kt, const ushort* G, int r0) {
    ushort* Lr = lds + (((bufi << 1) | ab) << 1 | kh) * 8192;
#pragma unroll
    for (int j = 0; j < 2; j++) {
      const int c = j * 512 + wave * 64 + lane;
      const int row = c >> 2, slot = c & 3;
      const int ss = slot ^ ((row >> 1) & 3);
      const ushort* g = G + (size_t)(r0 + row) * K + kt * 64 + kh * 32 + ss * 8;
      __builtin_amdgcn_global_load_lds(
          (const __attribute__((address_space(1))) void*)g,
          (__attribute__((address_space(3))) void*)(Lr + (j * 512 + wave * 64) * 8), 16, 0, 0);
    }
  };
  auto rdA = [&](int bufi, int kh, int m) -> bf16x8_t {
    const int row = wm * 128 + m * 16 + (lane & 15);
    const int slot = (lane >> 4) ^ ((row >> 1) & 3);
    return *reinterpret_cast<const bf16x8_t*>(lds + ((bufi << 2) | kh) * 8192 + row * 32 + slot * 8);
  };
  auto rdB = [&](int bufi, int kh, int nf) -> bf16x8_t {
    const int row = wn * 64 + nf * 16 + (lane & 15);
    const int slot = (lane >> 4) ^ ((row >> 1) & 3);
    return *reinterpret_cast<const bf16x8_t*>(lds + (((bufi << 1) | 1) << 1 | kh) * 8192 + row * 32 + slot * 8);
  };

  f32x4_t acc[8][4];
#pragma unroll
  for (int m = 0; m < 8; m++)
#pragma unroll
    for (int nf = 0; nf < 4; nf++) acc[m][nf] = (f32x4_t){0.f, 0.f, 0.f, 0.f};

  // prologue stages: t0 full tile + t1 kh0 (6 stages = 12 loads/wave)
  stage(0, 0, 0, 0, A, m0);  stage(0, 1, 0, 0, Bm, n0);
  stage(0, 0, 1, 0, A, m0);  stage(0, 1, 1, 0, Bm, n0);
  stage(1, 0, 0, 1, A, m0);  stage(1, 1, 0, 1, Bm, n0);
  asm volatile("s_waitcnt vmcnt(8)" ::: "memory");   // buf0-kh0 (A,B) landed
  __builtin_amdgcn_s_barrier();
  __builtin_amdgcn_sched_barrier(0);

  // prologue reads: the set consumed by t0.ph1
  bf16x8_t pA0 = rdA(0, 0, 0), pA1 = rdA(0, 0, 1), pA2 = rdA(0, 0, 2), pA3 = rdA(0, 0, 3);
  bf16x8_t B00 = rdB(0, 0, 0), B01 = rdB(0, 0, 1), B02 = rdB(0, 0, 2), B03 = rdB(0, 0, 3);
  bf16x8_t qA0, qA1, qA2, qA3, B10, B11, B12, B13;

  for (int t = 0; t < NKT; t++) {
    const int buf = t & 1;
    const int t1 = (t + 1 < NKT) ? t + 1 : NKT - 1;
    const int t2 = (t + 2 < NKT) ? t + 2 : NKT - 1;

    // ---- ph1: reads qA<-A(kh0,mh1); stage A-kh1(t1)->buf^1; MFMA(pA,B0)->mh0 ----
    qA0 = rdA(buf, 0, 4); qA1 = rdA(buf, 0, 5); qA2 = rdA(buf, 0, 6); qA3 = rdA(buf, 0, 7);
    stage(buf ^ 1, 0, 1, t1, A, m0);
    __builtin_amdgcn_s_setprio(1);
    MFMA_BLK(0, pA0, pA1, pA2, pA3, B00, B01, B02, B03)
    __builtin_amdgcn_s_setprio(0);
    asm volatile("s_waitcnt vmcnt(6)" ::: "memory");  // buf-kh1 (A,B) landed
    __builtin_amdgcn_s_barrier();
    __builtin_amdgcn_sched_barrier(0);

    // ---- ph2: reads pA<-A(kh1,mh0), B1<-B(kh1); stage B-kh1(t1)->buf^1; MFMA(qA,B0)->mh1 ----
    pA0 = rdA(buf, 1, 0); pA1 = rdA(buf, 1, 1); pA2 = rdA(buf, 1, 2); pA3 = rdA(buf, 1, 3);
    B10 = rdB(buf, 1, 0); B11 = rdB(buf, 1, 1); B12 = rdB(buf, 1, 2); B13 = rdB(buf, 1, 3);
    stage(buf ^ 1, 1, 1, t1, Bm, n0);
    __builtin_amdgcn_s_setprio(1);
    MFMA_BLK(4, qA0, qA1, qA2, qA3, B00, B01, B02, B03)
    __builtin_amdgcn_s_setprio(0);
    __builtin_amdgcn_s_barrier();
    __builtin_amdgcn_sched_barrier(0);

    // ---- ph3: reads qA<-A(kh1,mh1); stage A-kh0(t2)->buf; MFMA(pA,B1)->mh0 ----
    qA0 = rdA(buf, 1, 4); qA1 = rdA(buf, 1, 5); qA2 = rdA(buf, 1, 6); qA3 = rdA(buf, 1, 7);
    stage(buf, 0, 0, t2, A, m0);
    __builtin_amdgcn_s_setprio(1);
    MFMA_BLK(0, pA0, pA1, pA2, pA3, B10, B11, B12, B13)
    __builtin_amdgcn_s_setprio(0);
    asm volatile("s_waitcnt vmcnt(6)" ::: "memory");  // buf^1-kh0 (A,B) landed
    __builtin_amdgcn_s_barrier();
    __builtin_amdgcn_sched_barrier(0);

    // ---- ph4: reads pA<-A'(kh0,mh0), B0<-B'(kh0) from buf^1; stage B-kh0(t2)->buf; MFMA(qA,B1)->mh1 ----
    pA0 = rdA(buf ^ 1, 0, 0); pA1 = rdA(buf ^ 1, 0, 1); pA2 = rdA(buf ^ 1, 0, 2); pA3 = rdA(buf ^ 1, 0, 3);
    B00 = rdB(buf ^ 1, 0, 0); B01 = rdB(buf ^ 1, 0, 1); B02 = rdB(buf ^ 1, 0, 2); B03 = rdB(buf ^ 1, 0, 3);
    stage(buf, 1, 0, t2, Bm, n0);
    __builtin_amdgcn_s_setprio(1);
    MFMA_BLK(4, qA0, qA1, qA2, qA3, B10, B11, B12, B13)
    __builtin_amdgcn_s_setprio(0);
    __builtin_amdgcn_s_barrier();
    __builtin_amdgcn_sched_barrier(0);
  }
  asm volatile("s_waitcnt vmcnt(0)" ::: "memory");

  // epilogue: C/D layout col = lane&15, row = (lane>>4)*4 + reg
#pragma unroll
  for (int m = 0; m < 8; m++) {
    const int rb = m0 + wm * 128 + m * 16 + (lane >> 4) * 4;
#pragma unroll
    for (int nf = 0; nf < 4; nf++) {
      const int col = n0 + wn * 64 + nf * 16 + (lane & 15);
#pragma unroll
      for (int r = 0; r < 4; r++) {
        const float val = acc[m][nf][r];
        if (BF16OUT)
          ((ushort*)Cv)[(size_t)(rb + r) * N + col] = f2bf(val);
        else
          ((float*)Cv)[(size_t)(rb + r) * N + col] = val;
      }
    }
  }
}

// ---------------- thin GEMM (r9 structure) + uniform interleaved v-cast ----------------
// grid (4 splits, M/128, 2 which) = 512 blocks; each block also casts a
// 1/512 slice of v (2 float4/thread/iter) -- independent filler traffic.
__global__ __launch_bounds__(256) void gemm_thin2(const float* __restrict__ qin,
                                                  const float* __restrict__ kin,
                                                  const float* __restrict__ vin,
                                                  const ushort* __restrict__ oqb,
                                                  const ushort* __restrict__ okb,
                                                  float* __restrict__ P,
                                                  ushort* __restrict__ xb) {
  __shared__ ushort lds_a[128 * 32];
  __shared__ ushort lds_b[128 * 32];
  const int which = blockIdx.z;
  const float* A = which ? kin : qin;
  const ushort* Bm = which ? okb : oqb;
  const int t = threadIdx.x;
  const int wave = t >> 6, lane = t & 63;
  const int spl = blockIdx.x;
  const int m0 = blockIdx.y * 128;
  const int kb = spl * KSPL;
  const int wm = wave >> 1, wn = wave & 1;

  // v-cast slice: 512 blocks x 8192 float4s each
  const int fbid = (blockIdx.z * gridDim.y + blockIdx.y) * gridDim.x + blockIdx.x;
  const float4* v4 = reinterpret_cast<const float4*>(vin);
  ushort4* x4 = reinterpret_cast<ushort4*>(xb);
  const int vbase = fbid * 8192;

  f32x4_t acc[4][4];
#pragma unroll
  for (int i = 0; i < 4; i++)
#pragma unroll
    for (int j = 0; j < 4; j++) acc[i][j] = (f32x4_t){0.f, 0.f, 0.f, 0.f};

  const int srow = lane >> 2;
  const int skoff = (lane & 3) * 8;

  int it = 0;
  for (int k0 = kb; k0 < kb + KSPL; k0 += 32, ++it) {
    // v-cast filler: issue loads early
    const int vi0 = vbase + it * 512 + t;
    const int vi1 = vi0 + 256;
    const float4 va = v4[vi0], vb = v4[vi1];
    // A: fp32 load + convert + LDS write (fused cast)
#pragma unroll
    for (int j = 0; j < 2; j++) {
      const int g = j * 256 + t;
      const int row = g >> 2, slot = g & 3;
      const float4* gp = reinterpret_cast<const float4*>(A + (size_t)(m0 + row) * DM + k0 + slot * 8);
      const float4 f0 = gp[0], f1 = gp[1];
      union { ushort u[8]; bf16x8_t v; } pk;
      pk.u[0] = f2bf(f0.x); pk.u[1] = f2bf(f0.y); pk.u[2] = f2bf(f0.z); pk.u[3] = f2bf(f0.w);
      pk.u[4] = f2bf(f1.x); pk.u[5] = f2bf(f1.y); pk.u[6] = f2bf(f1.z); pk.u[7] = f2bf(f1.w);
      *reinterpret_cast<bf16x8_t*>(lds_a + row * 32 + slot * 8) = pk.v;
    }
    // B: bf16 via async global->LDS
#pragma unroll
    for (int i = 0; i < 2; i++) {
      const int rgrp = i * 4 + wave;
      const int row = rgrp * 16 + srow;
      const ushort* gb = Bm + (size_t)row * DM + (k0 + skoff);
      __builtin_amdgcn_global_load_lds(
          (const __attribute__((address_space(1))) void*)gb,
          (__attribute__((address_space(3))) void*)(lds_b + rgrp * 512), 16, 0, 0);
    }
    // v-cast filler: convert + store (independent of LDS/barrier flow)
    {
      ushort4 oa, ob;
      oa.x = f2bf(va.x); oa.y = f2bf(va.y); oa.z = f2bf(va.z); oa.w = f2bf(va.w);
      ob.x = f2bf(vb.x); ob.y = f2bf(vb.y); ob.z = f2bf(vb.z); ob.w = f2bf(vb.w);
      x4[vi0] = oa; x4[vi1] = ob;
    }
    __syncthreads();
    bf16x8_t af[4], bfr[4];
#pragma unroll
    for (int i = 0; i < 4; i++) {
      af[i]  = *reinterpret_cast<const bf16x8_t*>(
          lds_a + (wm * 64 + i * 16 + (lane & 15)) * 32 + (lane >> 4) * 8);
      bfr[i] = *reinterpret_cast<const bf16x8_t*>(
          lds_b + (wn * 64 + i * 16 + (lane & 15)) * 32 + (lane >> 4) * 8);
    }
#pragma unroll
    for (int i = 0; i < 4; i++)
#pragma unroll
      for (int j = 0; j < 4; j++)
        acc[i][j] = __builtin_amdgcn_mfma_f32_16x16x32_bf16(af[i], bfr[j], acc[i][j], 0, 0, 0);
    __syncthreads();
  }

  float* Pp = P + (size_t)which * (4ull * R_TOT * 128) + (size_t)spl * ((size_t)R_TOT * 128);
#pragma unroll
  for (int i = 0; i < 4; i++) {
    const int rb = m0 + wm * 64 + i * 16 + (lane >> 4) * 4;
#pragma unroll
    for (int j = 0; j < 4; j++) {
      const int col = wn * 64 + j * 16 + (lane & 15);
#pragma unroll
      for (int r = 0; r < 4; r++)
        Pp[(size_t)(rb + r) * 128 + col] = acc[i][j][r];
    }
  }
}

// ---------------- merged performer features from split-K partials ----------------
__global__ __launch_bounds__(256) void feat2x2(const float* __restrict__ P,
                                               float* __restrict__ qf,
                                               float* __restrict__ kf) {
  const int which = blockIdx.y;
  const float* Pb = P + (size_t)which * (4ull * R_TOT * 128);
  float* F = which ? kf : qf;
  const int g = blockIdx.x * 256 + threadIdx.x;     // 131072 total
  const int row = g >> 4, h = g & 15;
  float4 a = {0.f, 0.f, 0.f, 0.f}, c = {0.f, 0.f, 0.f, 0.f};
#pragma unroll
  for (int s = 0; s < 4; s++) {
    const float4* xp = reinterpret_cast<const float4*>(
        Pb + (size_t)s * ((size_t)R_TOT * 128) + (size_t)row * 128 + h * NFEAT);
    const float4 u = xp[0], w = xp[1];
    a.x += u.x; a.y += u.y; a.z += u.z; a.w += u.w;
    c.x += w.x; c.y += w.y; c.z += w.z; c.w += w.w;
  }
  float x[8] = {a.x, a.y, a.z, a.w, c.x, c.y, c.z, c.w};
  float f[8], s = 0.f;
#pragma unroll
  for (int n = 0; n < 8; n++) { f[n] = __expf(-0.5f * x[n] * x[n]); s += f[n]; }
  const float inv = 1.f / (s + EPSF);
  const int b = row >> 12, sidx = row & 4095;
  float* out = F + ((size_t)(h * 2 + b) * 4096 + sidx) * 8;
  float4 o0 = {f[0] * inv, f[1] * inv, f[2] * inv, f[3] * inv};
  float4 o1 = {f[4] * inv, f[5] * inv, f[6] * inv, f[7] * inv};
  reinterpret_cast<float4*>(out)[0] = o0;
  reinterpret_cast<float4*>(out)[1] = o1;
}

// ---------------- per-chunk partial sums: KV_c[8][128], K_c[8] ----------------
__global__ __launch_bounds__(128) void chunk_sum_kernel(const float* __restrict__ KF,
                                                        const ushort* __restrict__ VH,
                                                        float* __restrict__ CKV,
                                                        float* __restrict__ CK) {
  const int cid = blockIdx.x;
  const int c = cid & 31, bh = cid >> 5, b = bh >> 4, h = bh & 15;
  const int d = threadIdx.x;
  __shared__ float s_kf[CHUNK * 8];
  const size_t fbase = ((size_t)(h * 2 + b) * 4096 + (size_t)c * CHUNK) * 8;
  {
    float4 a0 = *reinterpret_cast<const float4*>(KF + fbase + d * 8);
    float4 a1 = *reinterpret_cast<const float4*>(KF + fbase + d * 8 + 4);
    *reinterpret_cast<float4*>(s_kf + d * 8) = a0;
    *reinterpret_cast<float4*>(s_kf + d * 8 + 4) = a1;
  }
  __syncthreads();
  float kv[8] = {0, 0, 0, 0, 0, 0, 0, 0};
  float ks = 0.f;
  const ushort* vp = VH + ((size_t)b * S_LEN + (size_t)c * CHUNK) * DM + h * DK + d;
  for (int s = 0; s < CHUNK; s++) {
    const float v = bf2f(vp[(size_t)s * DM]);
#pragma unroll
    for (int n = 0; n < 8; n++) kv[n] += s_kf[s * 8 + n] * v;
    ks += s_kf[s * 8 + (d & 7)];
  }
#pragma unroll
  for (int n = 0; n < 8; n++) CKV[((size_t)cid * 8 + n) * 128 + d] = kv[n];
  if (d < 8) CK[cid * 8 + d] = ks;
}

// ---------------- exclusive prefix over chunks, parallel ----------------
__global__ __launch_bounds__(128) void chunk_scan2(float* __restrict__ CKV,
                                                   float* __restrict__ CK) {
  const int bh = blockIdx.x >> 3, n = blockIdx.x & 7;
  const int d = threadIdx.x;
  float v[NCHUNK];
#pragma unroll
  for (int c = 0; c < NCHUNK; c++)
    v[c] = CKV[((size_t)(bh * NCHUNK + c) * 8 + n) * 128 + d];
  float run = 0.f;
#pragma unroll
  for (int c = 0; c < NCHUNK; c++) {
    const float tv = v[c];
    CKV[((size_t)(bh * NCHUNK + c) * 8 + n) * 128 + d] = run;
    run += tv;
  }
  if (d < 32) {
    const int i = (bh * NCHUNK + d) * 8 + n;
    const float orig = CK[i];
    float inc = orig;
#pragma unroll
    for (int off = 1; off < 32; off <<= 1) {
      const float o = __shfl_up(inc, off, 32);
      if (d >= off) inc += o;
    }
    CK[i] = inc - orig;   // exclusive
  }
}

// ---------------- in-chunk causal scan + query ----------------
__global__ __launch_bounds__(128) void attn_scan_kernel(const float* __restrict__ QF,
                                                        const float* __restrict__ KF,
                                                        const ushort* __restrict__ VH,
                                                        const float* __restrict__ CKV,
                                                        const float* __restrict__ CK,
                                                        ushort* __restrict__ AO) {
  const int cid = blockIdx.x;
  const int c = cid & 31, bh = cid >> 5, b = bh >> 4, h = bh & 15;
  const int d = threadIdx.x;
  __shared__ float s_qf[CHUNK * 8];
  __shared__ float s_kf[CHUNK * 8];
  const size_t fbase = ((size_t)(h * 2 + b) * 4096 + (size_t)c * CHUNK) * 8;
  {
    float4 a0 = *reinterpret_cast<const float4*>(QF + fbase + d * 8);
    float4 a1 = *reinterpret_cast<const float4*>(QF + fbase + d * 8 + 4);
    float4 b0 = *reinterpret_cast<const float4*>(KF + fbase + d * 8);
    float4 b1 = *reinterpret_cast<const float4*>(KF + fbase + d * 8 + 4);
    *reinterpret_cast<float4*>(s_qf + d * 8) = a0;
    *reinterpret_cast<float4*>(s_qf + d * 8 + 4) = a1;
    *reinterpret_cast<float4*>(s_kf + d * 8) = b0;
    *reinterpret_cast<float4*>(s_kf + d * 8 + 4) = b1;
  }
  float kv[8], krun[8];
#pragma unroll
  for (int n = 0; n < 8; n++) kv[n] = CKV[((size_t)cid * 8 + n) * 128 + d];
#pragma unroll
  for (int n = 0; n < 8; n++) krun[n] = CK[cid * 8 + n];
  __syncthreads();
  const size_t row0 = (size_t)b * S_LEN + (size_t)c * CHUNK;
  const ushort* vp = VH + row0 * DM + h * DK + d;
  ushort* op = AO + row0 * DM + h * DK + d;
  for (int s = 0; s < CHUNK; s++) {
    const float v = bf2f(vp[(size_t)s * DM]);
    float num = 0.f, den = 0.f;
#pragma unroll
    for (int n = 0; n < 8; n++) {
      const float kf = s_kf[s * 8 + n];
      kv[n] += kf * v;       // inclusive update first
      krun[n] += kf;
      const float qf = s_qf[s * 8 + n];
      num += qf * kv[n];
      den += qf * krun[n];
    }
    op[(size_t)s * DM] = f2bf(num / (den + EPSF));
  }
}

extern "C" void kernel_launch(void* const* d_in, const int* in_sizes, int n_in,
                              void* d_out, int out_size, void* d_ws, size_t ws_size,
                              hipStream_t stream) {
  const float* q     = (const float*)d_in[0];
  const float* k     = (const float*)d_in[1];
  const float* v     = (const float*)d_in[2];
  const float* w_q   = (const float*)d_in[3];
  const float* w_k   = (const float*)d_in[4];
  const float* w_v   = (const float*)d_in[5];
  const float* w_o   = (const float*)d_in[6];
  const float* omega = (const float*)d_in[7];

  // ---- workspace layout (~93 MB) ----
  char* ws = (char*)d_ws;
  const size_t DD2 = (size_t)DM * DM * 2;            //  8 MB
  const size_t OD2 = (size_t)NH * NFEAT * DM * 2;    //  0.5 MB
  const size_t RD2 = (size_t)R_TOT * DM * 2;         // 32 MB
  const size_t X4  = (size_t)R_TOT * NH * NFEAT * 4; //  4 MB

  ushort* wvb = (ushort*)(ws);
  ushort* wob = (ushort*)(ws + DD2);
  ushort* oqb = (ushort*)(ws + 2 * DD2);
  ushort* okb = (ushort*)(ws + 2 * DD2 + OD2);
  ushort* xb  = (ushort*)(ws + 2 * DD2 + 2 * OD2);             // bf16 staging: v -> attn-out
  ushort* vhb = (ushort*)(ws + 2 * DD2 + 2 * OD2 + RD2);
  float*  xp4 = (float*) (ws + 2 * DD2 + 2 * OD2 + RD2);       // 2x4 fp32 partials (32MB) alias vhb (dead then)
  float*  qf  = (float*) (ws + 2 * DD2 + 2 * OD2 + 2 * RD2);
  float*  kf  = (float*) (ws + 2 * DD2 + 2 * OD2 + 2 * RD2 + X4);
  float*  ckv = (float*) (ws + 2 * DD2 + 2 * OD2 + 2 * RD2 + 2 * X4);
  float*  ck  = (float*) (ws + 2 * DD2 + 2 * OD2 + 2 * RD2 + 3 * X4);
  ushort* ao  = xb;

  // prep: weight casts + folds (v-cast rides inside gemm_thin2)
  prep_kernel<<<dim3(8448), 256, 0, stream>>>(w_v, w_o, w_q, w_k, omega,
                                              wvb, wob, oqb, okb);

  // q + k features: split-K thin GEMM (fused q/k cast + uniform v-cast slices)
  gemm_thin2<<<dim3(DM / KSPL, R_TOT / 128, 2), 256, 0, stream>>>(q, k, v, oqb, okb, xp4, xb);
  feat2x2<<<dim3(R_TOT * NH / 256, 2), 256, 0, stream>>>(xp4, qf, kf);

  // v projection (overwrites xp4 region -- xp4 is dead now)
  gemm256<1><<<dim3((R_TOT / 256) * (DM / 256)), 512, 0, stream>>>(xb, wvb, (void*)vhb, R_TOT, DM, DM);

  // causal linear attention scan
  chunk_sum_kernel<<<dim3(B_SZ * NH * NCHUNK), 128, 0, stream>>>(kf, vhb, ckv, ck);
  chunk_scan2<<<dim3(B_SZ * NH * 8), 128, 0, stream>>>(ckv, ck);
  attn_scan_kernel<<<dim3(B_SZ * NH * NCHUNK), 128, 0, stream>>>(qf, kf, vhb, ckv, ck, ao);

  // output projection
  gemm256<0><<<dim3((R_TOT / 256) * (DM / 256)), 512, 0, stream>>>(ao, wob, d_out, R_TOT, DM, DM);
}